// Round 7
// baseline (1607.473 us; speedup 1.0000x reference)
//
#include <hip/hip_runtime.h>
#include <hip/hip_bf16.h>
#include <hip/hip_cooperative_groups.h>
#include <math.h>
#include <stdint.h>

// HolomorphicEqProp: B=4096, D_IN=H=1024, D_OUT=256, steps=30.
// Round-7: cooperative persistent kernel with INVERTED residency vs R6:
// Wr slice (64 cols x 1024 k, 129 KB) lives in LDS for ALL steps (loaded
// once); h ping-pongs through global (XCD-local L2 by block swizzle);
// xproj slice + biases in registers; grid.sync() between steps.
// R6's floor was 4 MB/step of LDS traffic re-staging Wr; here Wr LDS writes
// happen once and per-step LDS traffic is 1 MB of conflict-free reads.

#define EPSF 1e-12f

namespace cg = cooperative_groups;

typedef short bf16x8 __attribute__((ext_vector_type(8)));
typedef float f32x4 __attribute__((ext_vector_type(4)));

struct Mods { float m[32]; };

__device__ __forceinline__ unsigned short f2bf(float f) {
  union { float f; unsigned u; } v; v.f = f;
  unsigned r = v.u + 0x7FFFu + ((v.u >> 16) & 1u);  // RNE
  return (unsigned short)(r >> 16);
}

// async global->LDS (only in gemm_bt: R1-validated pattern — compile-time
// dest, issue -> barrier -> read). R2/R3 hazard: never use with
// runtime-varying LDS dest across barriers.
__device__ __forceinline__ void async16(const void* g, void* l) {
  __builtin_amdgcn_global_load_lds(
      (__attribute__((address_space(1))) void*)(uintptr_t)(g),
      (__attribute__((address_space(3))) void*)(unsigned)(uintptr_t)(l),
      16, 0, 0);
}

__device__ __forceinline__ float block_reduce_sum(float x) {
#pragma unroll
  for (int o = 32; o > 0; o >>= 1) x += __shfl_down(x, o, 64);
  __shared__ float sm[8];
  int lane = threadIdx.x & 63, w = threadIdx.x >> 6;
  if (lane == 0) sm[w] = x;
  __syncthreads();
  float t = 0.f;
  if (threadIdx.x == 0) {
    int nw = (int)(blockDim.x >> 6);
    for (int i = 0; i < nw; ++i) t += sm[i];
  }
  return t;
}

// ---------------- spectral-norm setup (fp32, exact; validated) ----------

__global__ void spec_col_partial(const float* __restrict__ W, const float* __restrict__ u,
                                 float* __restrict__ v, int M, int N, int rowsPerBlock) {
  int j = blockIdx.x * blockDim.x + threadIdx.x;
  int i0 = blockIdx.y * rowsPerBlock;
  float acc = 0.f;
  for (int i = i0; i < i0 + rowsPerBlock; ++i)
    acc += W[(size_t)i * N + j] * u[i];
  atomicAdd(&v[j], acc);
}

__global__ void vec_norm2(const float* __restrict__ v, float* __restrict__ out, int n) {
  float acc = 0.f;
  for (int i = threadIdx.x; i < n; i += blockDim.x) { float x = v[i]; acc += x * x; }
  float t = block_reduce_sum(acc);
  if (threadIdx.x == 0) *out = t;
}

__global__ void spec_row_sq(const float* __restrict__ W, const float* __restrict__ v,
                            float* __restrict__ usq, int N) {
  int i = blockIdx.x;
  float acc = 0.f;
  for (int j = threadIdx.x; j < N; j += blockDim.x)
    acc += W[(size_t)i * N + j] * v[j];
  float r = block_reduce_sum(acc);
  if (threadIdx.x == 0) atomicAdd(usq, r * r);
}

__global__ void spec_finalize(float* S) {
  int m = threadIdx.x;
  if (m < 3) {
    float nv = sqrtf(S[m]);
    float inv = 1.f / (nv + EPSF);
    float u2sq = S[3 + m] * inv * inv;
    float nu = sqrtf(u2sq);
    float sigma = u2sq / (nu + EPSF);
    S[6 + m] = 1.f / sigma;
  }
  if (m == 3) S[9] = 1.0f;
}

__global__ void cvt_scaled(const float4* __restrict__ W, const float* __restrict__ sp,
                           ushort4* __restrict__ o, int n4) {
  float s = *sp;
  for (int i = blockIdx.x * blockDim.x + threadIdx.x; i < n4; i += gridDim.x * blockDim.x) {
    float4 w = W[i];
    ushort4 r;
    r.x = f2bf(w.x * s); r.y = f2bf(w.y * s); r.z = f2bf(w.z * s); r.w = f2bf(w.w * s);
    o[i] = r;
  }
}

// C = A[M,K] . B[N,K]^T + bias[n], fp32 out. 64x128 tile (validated R5).
__global__ __launch_bounds__(256) void gemm_bt0(
    const unsigned short* __restrict__ A, const unsigned short* __restrict__ B,
    const float* __restrict__ bias, float* __restrict__ outF,
    int M, int N, int K) {
  constexpr int BM = 64, BN = 128, BK = 32;
  __shared__ __align__(16) unsigned short As[BM * BK];
  __shared__ __align__(16) unsigned short Bs[BN * BK];
  const int tid = threadIdx.x;
  const int wave = tid >> 6, lane = tid & 63;
  const int m0 = blockIdx.x * BM, n0 = blockIdx.y * BN;
  const int wm = (wave >> 1) * 32, wn = (wave & 1) * 64;
  const int lrow = lane & 15, quad = lane >> 4;

  f32x4 acc[2][4] = {};

  for (int k0 = 0; k0 < K; k0 += BK) {
    {
      int e = tid * 8;
      int r = e >> 5, c = e & 31;
      async16(&A[(size_t)(m0 + r) * K + k0 + c], &As[e]);
#pragma unroll
      for (int inst = 0; inst < 2; ++inst) {
        int eb = inst * 2048 + tid * 8;
        int rb = eb >> 5, cb = eb & 31;
        async16(&B[(size_t)(n0 + rb) * K + k0 + cb], &Bs[eb]);
      }
    }
    __syncthreads();

    bf16x8 af[2], bfr[4];
#pragma unroll
    for (int i = 0; i < 2; ++i)
      af[i] = *(const bf16x8*)&As[(wm + i * 16 + lrow) * BK + quad * 8];
#pragma unroll
    for (int j = 0; j < 4; ++j)
      bfr[j] = *(const bf16x8*)&Bs[(wn + j * 16 + lrow) * BK + quad * 8];
#pragma unroll
    for (int i = 0; i < 2; ++i)
#pragma unroll
      for (int j = 0; j < 4; ++j)
        acc[i][j] = __builtin_amdgcn_mfma_f32_16x16x32_bf16(af[i], bfr[j], acc[i][j], 0, 0, 0);
    __syncthreads();
  }

#pragma unroll
  for (int i = 0; i < 2; ++i)
#pragma unroll
    for (int j = 0; j < 4; ++j) {
      int col = n0 + wn + j * 16 + lrow;
      float bv = bias[col];
#pragma unroll
      for (int r = 0; r < 4; ++r) {
        int row = m0 + wm + i * 16 + quad * 4 + r;
        outF[(size_t)row * N + col] = acc[i][j][r] + bv;
      }
    }
}

// ---------------- cooperative RNN: steps 0..29, Wr-resident-in-LDS --------
// 256 blocks x 512 threads, 1 block/CU. Block (mt,nt): M rows [mt*256,+256),
// N cols [nt*64,+64). Swizzle keeps each m-tile's h slice on one XCD.
// Wave w owns M-sub [w*32,+32) x all 64 cols (2x4 frags of 16x16x32).
__global__ __launch_bounds__(512, 2) void rnn_coop(
    const unsigned short* __restrict__ Wr,   // [1024][1024] bf16 (scaled)
    const float* __restrict__ xproj,         // [4096][1024] f32
    const float* __restrict__ b_rec,
    unsigned short* __restrict__ hA,         // ping
    unsigned short* __restrict__ hB,         // pong
    Mods mods) {
  __shared__ __align__(16) unsigned short ws[64 * 1032];  // Wr slice, +8 pad
  cg::grid_group grid = cg::this_grid();

  const int tid = threadIdx.x;
  const int w = tid >> 6, lane = tid & 63;
  const int lrow = lane & 15, quad = lane >> 4;
  const int bid = (int)blockIdx.x;
  const int mt = (bid & 7) * 2 + ((bid >> 3) & 1);
  const int nt = bid >> 4;
  const int m0 = mt * 256 + w * 32;   // wave's M base
  const int n0 = nt * 64;             // block's N base

  // ---- Wr slice -> LDS (once). lane r = tid&63 -> row, conflict-free writes.
  {
    int r = tid & 63, s = tid >> 6;
    const unsigned short* src = Wr + (size_t)(n0 + r) * 1024 + s * 128;
    unsigned short* dst = ws + r * 1032 + s * 128;
#pragma unroll
    for (int j = 0; j < 16; ++j)
      *(bf16x8*)(dst + j * 8) = *(const bf16x8*)(src + j * 8);
  }

  // ---- xproj slice + bias -> registers (C-layout)
  float xpr[2][4][4], brec[4];
#pragma unroll
  for (int nf = 0; nf < 4; ++nf) brec[nf] = b_rec[n0 + nf * 16 + lrow];
#pragma unroll
  for (int mf = 0; mf < 2; ++mf)
#pragma unroll
    for (int nf = 0; nf < 4; ++nf)
#pragma unroll
      for (int r = 0; r < 4; ++r)
        xpr[mf][nf][r] =
            xproj[(size_t)(m0 + mf * 16 + quad * 4 + r) * 1024 + n0 + nf * 16 + lrow];

  // ---- t=0: h = tanh(xproj + b_rec), mod(0)=1 (h_prev = 0)
  unsigned short* cur = hA;
  unsigned short* nxt = hB;
#pragma unroll
  for (int mf = 0; mf < 2; ++mf)
#pragma unroll
    for (int nf = 0; nf < 4; ++nf)
#pragma unroll
      for (int r = 0; r < 4; ++r)
        cur[(size_t)(m0 + mf * 16 + quad * 4 + r) * 1024 + n0 + nf * 16 + lrow] =
            f2bf(tanhf(xpr[mf][nf][r] + brec[nf]));

  __syncthreads();  // ws ready for all waves

  // ---- steps t = 1..29
#pragma unroll 1
  for (int t = 1; t < 30; ++t) {
    grid.sync();    // h(t-1) fully written, device-visible
    const float mod = mods.m[t];
    f32x4 acc[2][4] = {};
    // a-frag prefetch pipeline (registers, static indices only)
    bf16x8 a0 = *(const bf16x8*)&cur[(size_t)(m0 + lrow) * 1024 + quad * 8];
    bf16x8 a1 = *(const bf16x8*)&cur[(size_t)(m0 + 16 + lrow) * 1024 + quad * 8];
#pragma unroll 2
    for (int kc = 0; kc < 32; ++kc) {
      int kn = (kc + 1) & 31;  // kc=31 wraps to 0: valid addr, result unused
      bf16x8 p0 = *(const bf16x8*)&cur[(size_t)(m0 + lrow) * 1024 + kn * 32 + quad * 8];
      bf16x8 p1 = *(const bf16x8*)&cur[(size_t)(m0 + 16 + lrow) * 1024 + kn * 32 + quad * 8];
#pragma unroll
      for (int nf = 0; nf < 4; ++nf) {
        bf16x8 b = *(const bf16x8*)&ws[(nf * 16 + lrow) * 1032 + kc * 32 + quad * 8];
        acc[0][nf] = __builtin_amdgcn_mfma_f32_16x16x32_bf16(a0, b, acc[0][nf], 0, 0, 0);
        acc[1][nf] = __builtin_amdgcn_mfma_f32_16x16x32_bf16(a1, b, acc[1][nf], 0, 0, 0);
      }
      a0 = p0; a1 = p1;
    }
#pragma unroll
    for (int mf = 0; mf < 2; ++mf)
#pragma unroll
      for (int nf = 0; nf < 4; ++nf)
#pragma unroll
        for (int r = 0; r < 4; ++r) {
          float hv = tanhf(xpr[mf][nf][r] + (acc[mf][nf][r] + brec[nf]) * mod);
          nxt[(size_t)(m0 + mf * 16 + quad * 4 + r) * 1024 + n0 + nf * 16 + lrow] = f2bf(hv);
        }
    unsigned short* tmp = cur; cur = nxt; nxt = tmp;
  }
  // final h (t=29) lives in hB (odd step count)
}

extern "C" void kernel_launch(void* const* d_in, const int* in_sizes, int n_in,
                              void* d_out, int out_size, void* d_ws, size_t ws_size,
                              hipStream_t stream) {
  const float* x     = (const float*)d_in[0];
  const float* W_in  = (const float*)d_in[1];
  const float* b_in  = (const float*)d_in[2];
  const float* W_rec = (const float*)d_in[3];
  const float* b_rec = (const float*)d_in[4];
  const float* W_out = (const float*)d_in[5];
  const float* b_out = (const float*)d_in[6];
  const float* u_in  = (const float*)d_in[7];
  const float* u_rec = (const float*)d_in[8];
  const float* u_out = (const float*)d_in[9];

  const int B = 4096, DIN = 1024, H = 1024, DOUT = 256;

  char* w = (char*)d_ws;
  float* S = (float*)w;
  float* v_in = S + 256;
  float* v_rec = v_in + 1024;
  float* v_out = v_rec + 1024;
  unsigned short* Wi_bf = (unsigned short*)(w + (1 << 14));
  unsigned short* Wr_bf = Wi_bf + (size_t)H * DIN;
  unsigned short* Wo_bf = Wr_bf + (size_t)H * H;
  unsigned short* x_bf  = Wo_bf + (size_t)DOUT * H;
  float* xproj = (float*)(x_bf + (size_t)B * DIN);
  unsigned short* hA = (unsigned short*)(xproj + (size_t)B * H);
  unsigned short* hB = hA + (size_t)B * H;

  hipMemsetAsync(w, 0, 1 << 14, stream);

  dim3 t256(256);
  spec_col_partial<<<dim3(DIN / 256, H / 64), t256, 0, stream>>>(W_in, u_in, v_in, H, DIN, 64);
  spec_col_partial<<<dim3(H / 256, H / 64), t256, 0, stream>>>(W_rec, u_rec, v_rec, H, H, 64);
  spec_col_partial<<<dim3(H / 256, DOUT / 64), t256, 0, stream>>>(W_out, u_out, v_out, DOUT, H, 64);
  vec_norm2<<<1, t256, 0, stream>>>(v_in, &S[0], DIN);
  vec_norm2<<<1, t256, 0, stream>>>(v_rec, &S[1], H);
  vec_norm2<<<1, t256, 0, stream>>>(v_out, &S[2], H);
  spec_row_sq<<<H, t256, 0, stream>>>(W_in, v_in, &S[3], DIN);
  spec_row_sq<<<H, t256, 0, stream>>>(W_rec, v_rec, &S[4], H);
  spec_row_sq<<<DOUT, t256, 0, stream>>>(W_out, v_out, &S[5], H);
  spec_finalize<<<1, 64, 0, stream>>>(S);

  cvt_scaled<<<512, t256, 0, stream>>>((const float4*)W_in, &S[6], (ushort4*)Wi_bf, H * DIN / 4);
  cvt_scaled<<<512, t256, 0, stream>>>((const float4*)W_rec, &S[7], (ushort4*)Wr_bf, H * H / 4);
  cvt_scaled<<<128, t256, 0, stream>>>((const float4*)W_out, &S[8], (ushort4*)Wo_bf, DOUT * H / 4);
  cvt_scaled<<<1024, t256, 0, stream>>>((const float4*)x, &S[9], (ushort4*)x_bf, B * DIN / 4);

  // xproj = x @ Wi_n^T + b_in (fp32)
  gemm_bt0<<<dim3(B / 64, H / 128), t256, 0, stream>>>(
      x_bf, Wi_bf, b_in, xproj, B, H, DIN);

  // steps 0..29 in one cooperative kernel (Wr resident in LDS)
  Mods mods;
  for (int t = 0; t < 32; ++t) mods.m[t] = (float)(1.0 + 0.1 * sin(0.3 * (double)t));
  {
    void* args[] = {(void*)&Wr_bf, (void*)&xproj, (void*)&b_rec,
                    (void*)&hA, (void*)&hB, (void*)&mods};
    hipLaunchCooperativeKernel((const void*)rnn_coop, dim3(256), dim3(512),
                               args, 0, stream);
  }

  // out = h29 @ Wo_n^T + b_out  (h29 in hB: 29 swaps from hA)
  gemm_bt0<<<dim3(B / 64, DOUT / 128), t256, 0, stream>>>(
      hB, Wo_bf, b_out, (float*)d_out, B, DOUT, H);
}

// Round 8
// 1059.357 us; speedup vs baseline: 1.5174x; 1.5174x over previous
//
#include <hip/hip_runtime.h>
#include <hip/hip_bf16.h>
#include <math.h>
#include <stdint.h>

// HolomorphicEqProp: B=4096, D_IN=H=1024, D_OUT=256, steps=30.
// Round-8: R7's Wr-resident-in-LDS cooperative kernel, with
//  (1) grid.sync() (~40us/step, the R7 bottleneck) replaced by per-group
//      16-block barriers (h-slice dependency groups are closed under bid&15),
//  (2) a-frag prefetch depth 4 (compile-time-indexed ring; R4 scratch lesson),
//  (3) xproj GEMM folded into the coop kernel (Wi staged in ws before Wr),
//  (4) setup chain fused 11 -> 4 kernels.

#define EPSF 1e-12f

typedef short bf16x8 __attribute__((ext_vector_type(8)));
typedef float f32x4 __attribute__((ext_vector_type(4)));

struct Mods { float m[32]; };

__device__ __forceinline__ unsigned short f2bf(float f) {
  union { float f; unsigned u; } v; v.f = f;
  unsigned r = v.u + 0x7FFFu + ((v.u >> 16) & 1u);  // RNE
  return (unsigned short)(r >> 16);
}

// async global->LDS (only in gemm_bt0: R1-validated pattern)
__device__ __forceinline__ void async16(const void* g, void* l) {
  __builtin_amdgcn_global_load_lds(
      (__attribute__((address_space(1))) void*)(uintptr_t)(g),
      (__attribute__((address_space(3))) void*)(unsigned)(uintptr_t)(l),
      16, 0, 0);
}

__device__ __forceinline__ float block_reduce_sum(float x) {
#pragma unroll
  for (int o = 32; o > 0; o >>= 1) x += __shfl_down(x, o, 64);
  __shared__ float sm[8];
  int lane = threadIdx.x & 63, w = threadIdx.x >> 6;
  if (lane == 0) sm[w] = x;
  __syncthreads();
  float t = 0.f;
  if (threadIdx.x == 0) {
    int nw = (int)(blockDim.x >> 6);
    for (int i = 0; i < nw; ++i) t += sm[i];
  }
  return t;
}

// ---------------- fused spectral-norm setup (fp32, exact) ----------------

// v[z] = W_z^T u_z, accumulated 64 rows per block. All W have N=1024 cols.
__global__ void spec_col3(const float* __restrict__ Wi, const float* __restrict__ Wr,
                          const float* __restrict__ Wo, const float* __restrict__ ui,
                          const float* __restrict__ ur, const float* __restrict__ uo,
                          float* __restrict__ v) {
  int z = blockIdx.z;
  const float* W = (z == 0) ? Wi : (z == 1) ? Wr : Wo;
  const float* u = (z == 0) ? ui : (z == 1) ? ur : uo;
  int M = (z == 2) ? 256 : 1024;
  int i0 = blockIdx.y * 64;
  if (i0 >= M) return;
  int j = blockIdx.x * blockDim.x + threadIdx.x;
  float acc = 0.f;
  for (int i = i0; i < i0 + 64; ++i)
    acc += W[(size_t)i * 1024 + j] * u[i];
  atomicAdd(&v[z * 1024 + j], acc);
}

// S[z] = ||v_z||^2, one block per z
__global__ void norm3(const float* __restrict__ v, float* __restrict__ S) {
  int z = blockIdx.x;
  float acc = 0.f;
  for (int i = threadIdx.x; i < 1024; i += blockDim.x) {
    float x = v[z * 1024 + i];
    acc += x * x;
  }
  float t = block_reduce_sum(acc);
  if (threadIdx.x == 0) S[z] = t;
}

// S[3+z] += (W_z[row,:] . v_z)^2   (2304 blocks)
__global__ void rowsq3(const float* __restrict__ Wi, const float* __restrict__ Wr,
                       const float* __restrict__ Wo, const float* __restrict__ v,
                       float* __restrict__ S) {
  int bid = blockIdx.x;
  int z = (bid < 1024) ? 0 : (bid < 2048) ? 1 : 2;
  int row = bid - ((z == 0) ? 0 : (z == 1) ? 1024 : 2048);
  const float* W = (z == 0) ? Wi : (z == 1) ? Wr : Wo;
  const float* vv = v + z * 1024;
  float acc = 0.f;
  for (int j = threadIdx.x; j < 1024; j += blockDim.x)
    acc += W[(size_t)row * 1024 + j] * vv[j];
  float r = block_reduce_sum(acc);
  if (threadIdx.x == 0) atomicAdd(&S[3 + z], r * r);
}

// S: [0..2]=||v||^2, [3..5]=sum r_i^2, [6..8]=1/sigma
__global__ void spec_finalize(float* S) {
  int m = threadIdx.x;
  if (m < 3) {
    float nv = sqrtf(S[m]);
    float inv = 1.f / (nv + EPSF);
    float u2sq = S[3 + m] * inv * inv;
    float nu = sqrtf(u2sq);
    float sigma = u2sq / (nu + EPSF);
    S[6 + m] = 1.f / sigma;
  }
}

__device__ __forceinline__ ushort4 cvt4e(float4 w, float s) {
  ushort4 r;
  r.x = f2bf(w.x * s); r.y = f2bf(w.y * s); r.z = f2bf(w.z * s); r.w = f2bf(w.w * s);
  return r;
}

// all four bf16 conversions in one kernel
__global__ void cvt_all(const float4* __restrict__ Wi, const float4* __restrict__ Wr,
                        const float4* __restrict__ Wo, const float4* __restrict__ x,
                        const float* __restrict__ S,
                        ushort4* __restrict__ oWi, ushort4* __restrict__ oWr,
                        ushort4* __restrict__ oWo, ushort4* __restrict__ ox) {
  float s6 = S[6], s7 = S[7], s8 = S[8];
  int stride = gridDim.x * blockDim.x;
  int t0 = blockIdx.x * blockDim.x + threadIdx.x;
  for (int i = t0; i < 262144; i += stride) oWi[i] = cvt4e(Wi[i], s6);
  for (int i = t0; i < 262144; i += stride) oWr[i] = cvt4e(Wr[i], s7);
  for (int i = t0; i < 65536; i += stride) oWo[i] = cvt4e(Wo[i], s8);
  for (int i = t0; i < 1048576; i += stride) ox[i] = cvt4e(x[i], 1.0f);
}

// C = A[M,K] . B[N,K]^T + bias[n], fp32 out. 64x128 tile (validated R5/R7).
__global__ __launch_bounds__(256) void gemm_bt0(
    const unsigned short* __restrict__ A, const unsigned short* __restrict__ B,
    const float* __restrict__ bias, float* __restrict__ outF,
    int M, int N, int K) {
  constexpr int BM = 64, BN = 128, BK = 32;
  __shared__ __align__(16) unsigned short As[BM * BK];
  __shared__ __align__(16) unsigned short Bs[BN * BK];
  const int tid = threadIdx.x;
  const int wave = tid >> 6, lane = tid & 63;
  const int m0 = blockIdx.x * BM, n0 = blockIdx.y * BN;
  const int wm = (wave >> 1) * 32, wn = (wave & 1) * 64;
  const int lrow = lane & 15, quad = lane >> 4;

  f32x4 acc[2][4] = {};

  for (int k0 = 0; k0 < K; k0 += BK) {
    {
      int e = tid * 8;
      int r = e >> 5, c = e & 31;
      async16(&A[(size_t)(m0 + r) * K + k0 + c], &As[e]);
#pragma unroll
      for (int inst = 0; inst < 2; ++inst) {
        int eb = inst * 2048 + tid * 8;
        int rb = eb >> 5, cb = eb & 31;
        async16(&B[(size_t)(n0 + rb) * K + k0 + cb], &Bs[eb]);
      }
    }
    __syncthreads();

    bf16x8 af[2], bfr[4];
#pragma unroll
    for (int i = 0; i < 2; ++i)
      af[i] = *(const bf16x8*)&As[(wm + i * 16 + lrow) * BK + quad * 8];
#pragma unroll
    for (int j = 0; j < 4; ++j)
      bfr[j] = *(const bf16x8*)&Bs[(wn + j * 16 + lrow) * BK + quad * 8];
#pragma unroll
    for (int i = 0; i < 2; ++i)
#pragma unroll
      for (int j = 0; j < 4; ++j)
        acc[i][j] = __builtin_amdgcn_mfma_f32_16x16x32_bf16(af[i], bfr[j], acc[i][j], 0, 0, 0);
    __syncthreads();
  }

#pragma unroll
  for (int i = 0; i < 2; ++i)
#pragma unroll
    for (int j = 0; j < 4; ++j) {
      int col = n0 + wn + j * 16 + lrow;
      float bv = bias[col];
#pragma unroll
      for (int r = 0; r < 4; ++r) {
        int row = m0 + wm + i * 16 + quad * 4 + r;
        outF[(size_t)row * N + col] = acc[i][j][r] + bv;
      }
    }
}

// ---------------- cooperative RNN ----------------

// load a 64-row x 1024-col bf16 slice into ws (row stride 1032)
__device__ __forceinline__ void load_ws(const unsigned short* __restrict__ src,
                                        unsigned short* ws, int tid) {
  int r = tid & 63, s = tid >> 6;
  const unsigned short* p = src + (size_t)r * 1024 + s * 128;
  unsigned short* d = ws + r * 1032 + s * 128;
#pragma unroll
  for (int j = 0; j < 16; ++j)
    *(bf16x8*)(d + j * 8) = *(const bf16x8*)(p + j * 8);
}

// K-sweep: acc[mf][nf] += A[m-frags] . ws[n-frags]^T over k=1024.
// a-frag prefetch ring of depth 4, ALL indices compile-time constants.
__device__ __forceinline__ void ksweep(const unsigned short* __restrict__ a0p,
                                       const unsigned short* __restrict__ a1p,
                                       const unsigned short* ws, int lrow, int quad,
                                       f32x4 acc[2][4]) {
  bf16x8 pa0[4], pa1[4];
#pragma unroll
  for (int i = 0; i < 4; ++i) {
    pa0[i] = *(const bf16x8*)(a0p + i * 32);
    pa1[i] = *(const bf16x8*)(a1p + i * 32);
  }
#pragma unroll 1
  for (int kb = 0; kb < 32; kb += 4) {
#define PHASE(P)                                                                 \
    {                                                                            \
      const int kc = kb + P;                                                     \
      bf16x8 a0 = pa0[P], a1 = pa1[P];                                           \
      const int kn = (kc + 4) & 31;                                              \
      pa0[P] = *(const bf16x8*)(a0p + kn * 32);                                  \
      pa1[P] = *(const bf16x8*)(a1p + kn * 32);                                  \
      _Pragma("unroll")                                                          \
      for (int nf = 0; nf < 4; ++nf) {                                           \
        bf16x8 b = *(const bf16x8*)&ws[(nf * 16 + lrow) * 1032 + kc * 32 + quad * 8]; \
        acc[0][nf] = __builtin_amdgcn_mfma_f32_16x16x32_bf16(a0, b, acc[0][nf], 0, 0, 0); \
        acc[1][nf] = __builtin_amdgcn_mfma_f32_16x16x32_bf16(a1, b, acc[1][nf], 0, 0, 0); \
      }                                                                          \
    }
    PHASE(0) PHASE(1) PHASE(2) PHASE(3)
#undef PHASE
  }
}

// monotone 16-block group barrier; ctr starts at 0, target = 16*t.
// Release-add publishes this XCD's h writes; acquire-load invalidates caches.
__device__ __forceinline__ void group_barrier(unsigned* ctr, unsigned target) {
  __syncthreads();  // all waves' stores issued & drained
  if (threadIdx.x == 0) {
    __hip_atomic_fetch_add(ctr, 1u, __ATOMIC_RELEASE, __HIP_MEMORY_SCOPE_AGENT);
    while (__hip_atomic_load(ctr, __ATOMIC_ACQUIRE, __HIP_MEMORY_SCOPE_AGENT) < target)
      __builtin_amdgcn_s_sleep(2);
  }
  __syncthreads();
}

// 256 blocks x 512 threads, 1 block/CU (LDS-bound). Block (mt,nt):
// M rows [mt*256,+256), N cols [nt*64,+64). Group = blocks sharing mt
// (bid&15) — closed under the h dependency, swizzled onto one XCD.
__global__ __launch_bounds__(512, 1) void rnn_coop(
    const unsigned short* __restrict__ x_bf,  // [4096][1024] bf16
    const unsigned short* __restrict__ Wi,    // [1024][1024] bf16 (scaled)
    const unsigned short* __restrict__ Wr,    // [1024][1024] bf16 (scaled)
    const float* __restrict__ b_in,
    const float* __restrict__ b_rec,
    unsigned short* __restrict__ hA,
    unsigned short* __restrict__ hB,
    unsigned* __restrict__ bar,
    Mods mods) {
  __shared__ __align__(16) unsigned short ws[64 * 1032];

  const int tid = threadIdx.x;
  const int w = tid >> 6, lane = tid & 63;
  const int lrow = lane & 15, quad = lane >> 4;
  const int bid = (int)blockIdx.x;
  const int mt = (bid & 7) * 2 + ((bid >> 3) & 1);
  const int nt = bid >> 4;
  const int gid = bid & 15;
  const int m0 = mt * 256 + w * 32;
  const int n0 = nt * 64;
  unsigned* ctr = bar + gid * 32;  // 128 B per group

  float bin[4], brec[4];
#pragma unroll
  for (int nf = 0; nf < 4; ++nf) {
    bin[nf] = b_in[n0 + nf * 16 + lrow];
    brec[nf] = b_rec[n0 + nf * 16 + lrow];
  }

  // ---- phase A: xproj slice (in registers) via Wi slice in ws ----
  load_ws(Wi + (size_t)n0 * 1024, ws, tid);
  __syncthreads();
  float xpr[2][4][4];
  {
    f32x4 xacc[2][4] = {};
    ksweep(&x_bf[(size_t)(m0 + lrow) * 1024 + quad * 8],
           &x_bf[(size_t)(m0 + 16 + lrow) * 1024 + quad * 8], ws, lrow, quad, xacc);
#pragma unroll
    for (int mf = 0; mf < 2; ++mf)
#pragma unroll
      for (int nf = 0; nf < 4; ++nf)
#pragma unroll
        for (int r = 0; r < 4; ++r)
          xpr[mf][nf][r] = xacc[mf][nf][r] + bin[nf];
  }
  __syncthreads();  // all ws (Wi) reads done

  // ---- Wr slice -> ws (resident for all steps) ----
  load_ws(Wr + (size_t)n0 * 1024, ws, tid);

  // ---- t=0: h = tanh(xproj + b_rec), mod(0)=1, h_prev=0 ----
  unsigned short* cur = hA;
  unsigned short* nxt = hB;
#pragma unroll
  for (int mf = 0; mf < 2; ++mf)
#pragma unroll
    for (int nf = 0; nf < 4; ++nf)
#pragma unroll
      for (int r = 0; r < 4; ++r)
        cur[(size_t)(m0 + mf * 16 + quad * 4 + r) * 1024 + n0 + nf * 16 + lrow] =
            f2bf(tanhf(xpr[mf][nf][r] + brec[nf]));
  __syncthreads();  // ws (Wr) ready

  // ---- steps t = 1..29 ----
#pragma unroll 1
  for (int t = 1; t < 30; ++t) {
    group_barrier(ctr, 16u * (unsigned)t);  // h(t-1) of this group visible
    const float mod = mods.m[t];
    f32x4 acc[2][4] = {};
    ksweep(&cur[(size_t)(m0 + lrow) * 1024 + quad * 8],
           &cur[(size_t)(m0 + 16 + lrow) * 1024 + quad * 8], ws, lrow, quad, acc);
#pragma unroll
    for (int mf = 0; mf < 2; ++mf)
#pragma unroll
      for (int nf = 0; nf < 4; ++nf)
#pragma unroll
        for (int r = 0; r < 4; ++r) {
          float hv = tanhf(xpr[mf][nf][r] + (acc[mf][nf][r] + brec[nf]) * mod);
          nxt[(size_t)(m0 + mf * 16 + quad * 4 + r) * 1024 + n0 + nf * 16 + lrow] = f2bf(hv);
        }
    unsigned short* tmp = cur; cur = nxt; nxt = tmp;
  }
  // h29 ends in hB (odd number of steps after t=0)
}

extern "C" void kernel_launch(void* const* d_in, const int* in_sizes, int n_in,
                              void* d_out, int out_size, void* d_ws, size_t ws_size,
                              hipStream_t stream) {
  const float* x     = (const float*)d_in[0];
  const float* W_in  = (const float*)d_in[1];
  const float* b_in  = (const float*)d_in[2];
  const float* W_rec = (const float*)d_in[3];
  const float* b_rec = (const float*)d_in[4];
  const float* W_out = (const float*)d_in[5];
  const float* b_out = (const float*)d_in[6];
  const float* u_in  = (const float*)d_in[7];
  const float* u_rec = (const float*)d_in[8];
  const float* u_out = (const float*)d_in[9];

  const int B = 4096, H = 1024, DOUT = 256;

  char* w = (char*)d_ws;
  float* S = (float*)w;                          // 256 floats
  float* v = S + 256;                            // 3 x 1024 floats (ends 13312 B)
  unsigned* bar = (unsigned*)(w + 14336);        // 16 groups x 128 B (ends 16384)
  unsigned short* Wi_bf = (unsigned short*)(w + (1 << 14));
  unsigned short* Wr_bf = Wi_bf + (size_t)H * H;
  unsigned short* Wo_bf = Wr_bf + (size_t)H * H;
  unsigned short* x_bf  = Wo_bf + (size_t)DOUT * H;
  unsigned short* hA = x_bf + (size_t)B * H;
  unsigned short* hB = hA + (size_t)B * H;

  hipMemsetAsync(w, 0, 1 << 14, stream);  // zero S, v, barrier counters

  dim3 t256(256);
  spec_col3<<<dim3(4, 16, 3), t256, 0, stream>>>(W_in, W_rec, W_out, u_in, u_rec, u_out, v);
  norm3<<<3, t256, 0, stream>>>(v, S);
  rowsq3<<<2304, t256, 0, stream>>>(W_in, W_rec, W_out, v, S);
  spec_finalize<<<1, 64, 0, stream>>>(S);
  cvt_all<<<1024, t256, 0, stream>>>((const float4*)W_in, (const float4*)W_rec,
                                     (const float4*)W_out, (const float4*)x, S,
                                     (ushort4*)Wi_bf, (ushort4*)Wr_bf,
                                     (ushort4*)Wo_bf, (ushort4*)x_bf);

  Mods mods;
  for (int t = 0; t < 32; ++t) mods.m[t] = (float)(1.0 + 0.1 * sin(0.3 * (double)t));
  {
    void* args[] = {(void*)&x_bf, (void*)&Wi_bf, (void*)&Wr_bf, (void*)&b_in,
                    (void*)&b_rec, (void*)&hA, (void*)&hB, (void*)&bar, (void*)&mods};
    hipLaunchCooperativeKernel((const void*)rnn_coop, dim3(256), dim3(512),
                               args, 0, stream);
  }

  // out = h29 @ Wo_n^T + b_out
  gemm_bt0<<<dim3(B / 64, DOUT / 128), t256, 0, stream>>>(
      hB, Wo_bf, b_out, (float*)d_out, B, DOUT, H);
}

// Round 9
// 1011.883 us; speedup vs baseline: 1.5886x; 1.0469x over previous
//
#include <hip/hip_runtime.h>
#include <hip/hip_bf16.h>
#include <math.h>
#include <stdint.h>

// HolomorphicEqProp: B=4096, D_IN=H=1024, D_OUT=256, steps=30.
// Round-9: R8 cooperative kernel with the barrier-spin fixed:
//  - R8 spun on ACQUIRE loads -> one L2/L1 invalidate PER POLL per block
//    (cache thrash for the whole XCD; a-frag loads pushed to L3 latency).
//    Now: relaxed spin + ONE acquire load after success.
//  - a-frag prefetch ring deepened 4 -> 8 (covers the single post-invalidate
//    L3 latency burst; all indices compile-time per the R4 scratch lesson).

#define EPSF 1e-12f

typedef short bf16x8 __attribute__((ext_vector_type(8)));
typedef float f32x4 __attribute__((ext_vector_type(4)));

struct Mods { float m[32]; };

__device__ __forceinline__ unsigned short f2bf(float f) {
  union { float f; unsigned u; } v; v.f = f;
  unsigned r = v.u + 0x7FFFu + ((v.u >> 16) & 1u);  // RNE
  return (unsigned short)(r >> 16);
}

// async global->LDS (only in gemm_bt0: R1-validated pattern)
__device__ __forceinline__ void async16(const void* g, void* l) {
  __builtin_amdgcn_global_load_lds(
      (__attribute__((address_space(1))) void*)(uintptr_t)(g),
      (__attribute__((address_space(3))) void*)(unsigned)(uintptr_t)(l),
      16, 0, 0);
}

__device__ __forceinline__ float block_reduce_sum(float x) {
#pragma unroll
  for (int o = 32; o > 0; o >>= 1) x += __shfl_down(x, o, 64);
  __shared__ float sm[8];
  int lane = threadIdx.x & 63, w = threadIdx.x >> 6;
  if (lane == 0) sm[w] = x;
  __syncthreads();
  float t = 0.f;
  if (threadIdx.x == 0) {
    int nw = (int)(blockDim.x >> 6);
    for (int i = 0; i < nw; ++i) t += sm[i];
  }
  return t;
}

// ---------------- fused spectral-norm setup (fp32, exact) ----------------

__global__ void spec_col3(const float* __restrict__ Wi, const float* __restrict__ Wr,
                          const float* __restrict__ Wo, const float* __restrict__ ui,
                          const float* __restrict__ ur, const float* __restrict__ uo,
                          float* __restrict__ v) {
  int z = blockIdx.z;
  const float* W = (z == 0) ? Wi : (z == 1) ? Wr : Wo;
  const float* u = (z == 0) ? ui : (z == 1) ? ur : uo;
  int M = (z == 2) ? 256 : 1024;
  int i0 = blockIdx.y * 64;
  if (i0 >= M) return;
  int j = blockIdx.x * blockDim.x + threadIdx.x;
  float acc = 0.f;
  for (int i = i0; i < i0 + 64; ++i)
    acc += W[(size_t)i * 1024 + j] * u[i];
  atomicAdd(&v[z * 1024 + j], acc);
}

__global__ void norm3(const float* __restrict__ v, float* __restrict__ S) {
  int z = blockIdx.x;
  float acc = 0.f;
  for (int i = threadIdx.x; i < 1024; i += blockDim.x) {
    float x = v[z * 1024 + i];
    acc += x * x;
  }
  float t = block_reduce_sum(acc);
  if (threadIdx.x == 0) S[z] = t;
}

__global__ void rowsq3(const float* __restrict__ Wi, const float* __restrict__ Wr,
                       const float* __restrict__ Wo, const float* __restrict__ v,
                       float* __restrict__ S) {
  int bid = blockIdx.x;
  int z = (bid < 1024) ? 0 : (bid < 2048) ? 1 : 2;
  int row = bid - ((z == 0) ? 0 : (z == 1) ? 1024 : 2048);
  const float* W = (z == 0) ? Wi : (z == 1) ? Wr : Wo;
  const float* vv = v + z * 1024;
  float acc = 0.f;
  for (int j = threadIdx.x; j < 1024; j += blockDim.x)
    acc += W[(size_t)row * 1024 + j] * vv[j];
  float r = block_reduce_sum(acc);
  if (threadIdx.x == 0) atomicAdd(&S[3 + z], r * r);
}

__global__ void spec_finalize(float* S) {
  int m = threadIdx.x;
  if (m < 3) {
    float nv = sqrtf(S[m]);
    float inv = 1.f / (nv + EPSF);
    float u2sq = S[3 + m] * inv * inv;
    float nu = sqrtf(u2sq);
    float sigma = u2sq / (nu + EPSF);
    S[6 + m] = 1.f / sigma;
  }
}

__device__ __forceinline__ ushort4 cvt4e(float4 w, float s) {
  ushort4 r;
  r.x = f2bf(w.x * s); r.y = f2bf(w.y * s); r.z = f2bf(w.z * s); r.w = f2bf(w.w * s);
  return r;
}

__global__ void cvt_all(const float4* __restrict__ Wi, const float4* __restrict__ Wr,
                        const float4* __restrict__ Wo, const float4* __restrict__ x,
                        const float* __restrict__ S,
                        ushort4* __restrict__ oWi, ushort4* __restrict__ oWr,
                        ushort4* __restrict__ oWo, ushort4* __restrict__ ox) {
  float s6 = S[6], s7 = S[7], s8 = S[8];
  int stride = gridDim.x * blockDim.x;
  int t0 = blockIdx.x * blockDim.x + threadIdx.x;
  for (int i = t0; i < 262144; i += stride) oWi[i] = cvt4e(Wi[i], s6);
  for (int i = t0; i < 262144; i += stride) oWr[i] = cvt4e(Wr[i], s7);
  for (int i = t0; i < 65536; i += stride) oWo[i] = cvt4e(Wo[i], s8);
  for (int i = t0; i < 1048576; i += stride) ox[i] = cvt4e(x[i], 1.0f);
}

// C = A[M,K] . B[N,K]^T + bias[n], fp32 out. 64x128 tile (validated R5/R7).
__global__ __launch_bounds__(256) void gemm_bt0(
    const unsigned short* __restrict__ A, const unsigned short* __restrict__ B,
    const float* __restrict__ bias, float* __restrict__ outF,
    int M, int N, int K) {
  constexpr int BM = 64, BN = 128, BK = 32;
  __shared__ __align__(16) unsigned short As[BM * BK];
  __shared__ __align__(16) unsigned short Bs[BN * BK];
  const int tid = threadIdx.x;
  const int wave = tid >> 6, lane = tid & 63;
  const int m0 = blockIdx.x * BM, n0 = blockIdx.y * BN;
  const int wm = (wave >> 1) * 32, wn = (wave & 1) * 64;
  const int lrow = lane & 15, quad = lane >> 4;

  f32x4 acc[2][4] = {};

  for (int k0 = 0; k0 < K; k0 += BK) {
    {
      int e = tid * 8;
      int r = e >> 5, c = e & 31;
      async16(&A[(size_t)(m0 + r) * K + k0 + c], &As[e]);
#pragma unroll
      for (int inst = 0; inst < 2; ++inst) {
        int eb = inst * 2048 + tid * 8;
        int rb = eb >> 5, cb = eb & 31;
        async16(&B[(size_t)(n0 + rb) * K + k0 + cb], &Bs[eb]);
      }
    }
    __syncthreads();

    bf16x8 af[2], bfr[4];
#pragma unroll
    for (int i = 0; i < 2; ++i)
      af[i] = *(const bf16x8*)&As[(wm + i * 16 + lrow) * BK + quad * 8];
#pragma unroll
    for (int j = 0; j < 4; ++j)
      bfr[j] = *(const bf16x8*)&Bs[(wn + j * 16 + lrow) * BK + quad * 8];
#pragma unroll
    for (int i = 0; i < 2; ++i)
#pragma unroll
      for (int j = 0; j < 4; ++j)
        acc[i][j] = __builtin_amdgcn_mfma_f32_16x16x32_bf16(af[i], bfr[j], acc[i][j], 0, 0, 0);
    __syncthreads();
  }

#pragma unroll
  for (int i = 0; i < 2; ++i)
#pragma unroll
    for (int j = 0; j < 4; ++j) {
      int col = n0 + wn + j * 16 + lrow;
      float bv = bias[col];
#pragma unroll
      for (int r = 0; r < 4; ++r) {
        int row = m0 + wm + i * 16 + quad * 4 + r;
        outF[(size_t)row * N + col] = acc[i][j][r] + bv;
      }
    }
}

// ---------------- cooperative RNN ----------------

__device__ __forceinline__ void load_ws(const unsigned short* __restrict__ src,
                                        unsigned short* ws, int tid) {
  int r = tid & 63, s = tid >> 6;
  const unsigned short* p = src + (size_t)r * 1024 + s * 128;
  unsigned short* d = ws + r * 1032 + s * 128;
#pragma unroll
  for (int j = 0; j < 16; ++j)
    *(bf16x8*)(d + j * 8) = *(const bf16x8*)(p + j * 8);
}

// K-sweep with a-frag prefetch ring of depth 8; all indices compile-time.
__device__ __forceinline__ void ksweep(const unsigned short* __restrict__ a0p,
                                       const unsigned short* __restrict__ a1p,
                                       const unsigned short* ws, int lrow, int quad,
                                       f32x4 acc[2][4]) {
  bf16x8 pa0[8], pa1[8];
#pragma unroll
  for (int i = 0; i < 8; ++i) {
    pa0[i] = *(const bf16x8*)(a0p + i * 32);
    pa1[i] = *(const bf16x8*)(a1p + i * 32);
  }
#pragma unroll 1
  for (int kb = 0; kb < 32; kb += 8) {
#define PHASE(P)                                                                 \
    {                                                                            \
      const int kc = kb + P;                                                     \
      bf16x8 a0 = pa0[P], a1 = pa1[P];                                           \
      const int kn = (kc + 8) & 31;                                              \
      pa0[P] = *(const bf16x8*)(a0p + kn * 32);                                  \
      pa1[P] = *(const bf16x8*)(a1p + kn * 32);                                  \
      _Pragma("unroll")                                                          \
      for (int nf = 0; nf < 4; ++nf) {                                           \
        bf16x8 b = *(const bf16x8*)&ws[(nf * 16 + lrow) * 1032 + kc * 32 + quad * 8]; \
        acc[0][nf] = __builtin_amdgcn_mfma_f32_16x16x32_bf16(a0, b, acc[0][nf], 0, 0, 0); \
        acc[1][nf] = __builtin_amdgcn_mfma_f32_16x16x32_bf16(a1, b, acc[1][nf], 0, 0, 0); \
      }                                                                          \
    }
    PHASE(0) PHASE(1) PHASE(2) PHASE(3) PHASE(4) PHASE(5) PHASE(6) PHASE(7)
#undef PHASE
  }
}

// monotone 16-block group barrier. Release-add publishes h writes
// device-wide; spin uses RELAXED loads (no per-poll invalidate); ONE
// acquire load after success invalidates caches exactly once.
__device__ __forceinline__ void group_barrier(unsigned* ctr, unsigned target) {
  __syncthreads();  // all waves' stores issued & drained to L2
  if (threadIdx.x == 0) {
    __hip_atomic_fetch_add(ctr, 1u, __ATOMIC_RELEASE, __HIP_MEMORY_SCOPE_AGENT);
    while (__hip_atomic_load(ctr, __ATOMIC_RELAXED, __HIP_MEMORY_SCOPE_AGENT) < target)
      __builtin_amdgcn_s_sleep(2);
    // single acquire: orders all subsequent h reads, one cache-inv total
    (void)__hip_atomic_load(ctr, __ATOMIC_ACQUIRE, __HIP_MEMORY_SCOPE_AGENT);
  }
  __syncthreads();
}

// 256 blocks x 512 threads, 1 block/CU (LDS-bound). Block (mt,nt):
// M rows [mt*256,+256), N cols [nt*64,+64). Group = blocks sharing mt
// (bid&15) — closed under the h dependency, swizzled onto one XCD.
__global__ __launch_bounds__(512, 1) void rnn_coop(
    const unsigned short* __restrict__ x_bf,  // [4096][1024] bf16
    const unsigned short* __restrict__ Wi,    // [1024][1024] bf16 (scaled)
    const unsigned short* __restrict__ Wr,    // [1024][1024] bf16 (scaled)
    const float* __restrict__ b_in,
    const float* __restrict__ b_rec,
    unsigned short* __restrict__ hA,
    unsigned short* __restrict__ hB,
    unsigned* __restrict__ bar,
    Mods mods) {
  __shared__ __align__(16) unsigned short ws[64 * 1032];

  const int tid = threadIdx.x;
  const int w = tid >> 6, lane = tid & 63;
  const int lrow = lane & 15, quad = lane >> 4;
  const int bid = (int)blockIdx.x;
  const int mt = (bid & 7) * 2 + ((bid >> 3) & 1);
  const int nt = bid >> 4;
  const int gid = bid & 15;
  const int m0 = mt * 256 + w * 32;
  const int n0 = nt * 64;
  unsigned* ctr = bar + gid * 32;  // 128 B per group

  float bin[4], brec[4];
#pragma unroll
  for (int nf = 0; nf < 4; ++nf) {
    bin[nf] = b_in[n0 + nf * 16 + lrow];
    brec[nf] = b_rec[n0 + nf * 16 + lrow];
  }

  // ---- phase A: xproj slice (registers) via Wi slice in ws ----
  load_ws(Wi + (size_t)n0 * 1024, ws, tid);
  __syncthreads();
  float xpr[2][4][4];
  {
    f32x4 xacc[2][4] = {};
    ksweep(&x_bf[(size_t)(m0 + lrow) * 1024 + quad * 8],
           &x_bf[(size_t)(m0 + 16 + lrow) * 1024 + quad * 8], ws, lrow, quad, xacc);
#pragma unroll
    for (int mf = 0; mf < 2; ++mf)
#pragma unroll
      for (int nf = 0; nf < 4; ++nf)
#pragma unroll
        for (int r = 0; r < 4; ++r)
          xpr[mf][nf][r] = xacc[mf][nf][r] + bin[nf];
  }
  __syncthreads();  // all ws (Wi) reads done

  // ---- Wr slice -> ws (resident for all steps) ----
  load_ws(Wr + (size_t)n0 * 1024, ws, tid);

  // ---- t=0: h = tanh(xproj + b_rec), mod(0)=1, h_prev=0 ----
  unsigned short* cur = hA;
  unsigned short* nxt = hB;
#pragma unroll
  for (int mf = 0; mf < 2; ++mf)
#pragma unroll
    for (int nf = 0; nf < 4; ++nf)
#pragma unroll
      for (int r = 0; r < 4; ++r)
        cur[(size_t)(m0 + mf * 16 + quad * 4 + r) * 1024 + n0 + nf * 16 + lrow] =
            f2bf(tanhf(xpr[mf][nf][r] + brec[nf]));
  __syncthreads();  // ws (Wr) ready

  // ---- steps t = 1..29 ----
#pragma unroll 1
  for (int t = 1; t < 30; ++t) {
    group_barrier(ctr, 16u * (unsigned)t);  // h(t-1) of this group visible
    const float mod = mods.m[t];
    f32x4 acc[2][4] = {};
    ksweep(&cur[(size_t)(m0 + lrow) * 1024 + quad * 8],
           &cur[(size_t)(m0 + 16 + lrow) * 1024 + quad * 8], ws, lrow, quad, acc);
#pragma unroll
    for (int mf = 0; mf < 2; ++mf)
#pragma unroll
      for (int nf = 0; nf < 4; ++nf)
#pragma unroll
        for (int r = 0; r < 4; ++r) {
          float hv = tanhf(xpr[mf][nf][r] + (acc[mf][nf][r] + brec[nf]) * mod);
          nxt[(size_t)(m0 + mf * 16 + quad * 4 + r) * 1024 + n0 + nf * 16 + lrow] = f2bf(hv);
        }
    unsigned short* tmp = cur; cur = nxt; nxt = tmp;
  }
  // h29 ends in hB (odd number of steps after t=0)
}

extern "C" void kernel_launch(void* const* d_in, const int* in_sizes, int n_in,
                              void* d_out, int out_size, void* d_ws, size_t ws_size,
                              hipStream_t stream) {
  const float* x     = (const float*)d_in[0];
  const float* W_in  = (const float*)d_in[1];
  const float* b_in  = (const float*)d_in[2];
  const float* W_rec = (const float*)d_in[3];
  const float* b_rec = (const float*)d_in[4];
  const float* W_out = (const float*)d_in[5];
  const float* b_out = (const float*)d_in[6];
  const float* u_in  = (const float*)d_in[7];
  const float* u_rec = (const float*)d_in[8];
  const float* u_out = (const float*)d_in[9];

  const int B = 4096, H = 1024, DOUT = 256;

  char* w = (char*)d_ws;
  float* S = (float*)w;                          // 256 floats
  float* v = S + 256;                            // 3 x 1024 floats
  unsigned* bar = (unsigned*)(w + 14336);        // 16 groups x 128 B
  unsigned short* Wi_bf = (unsigned short*)(w + (1 << 14));
  unsigned short* Wr_bf = Wi_bf + (size_t)H * H;
  unsigned short* Wo_bf = Wr_bf + (size_t)H * H;
  unsigned short* x_bf  = Wo_bf + (size_t)DOUT * H;
  unsigned short* hA = x_bf + (size_t)B * H;
  unsigned short* hB = hA + (size_t)B * H;

  hipMemsetAsync(w, 0, 1 << 14, stream);  // zero S, v, barrier counters

  dim3 t256(256);
  spec_col3<<<dim3(4, 16, 3), t256, 0, stream>>>(W_in, W_rec, W_out, u_in, u_rec, u_out, v);
  norm3<<<3, t256, 0, stream>>>(v, S);
  rowsq3<<<2304, t256, 0, stream>>>(W_in, W_rec, W_out, v, S);
  spec_finalize<<<1, 64, 0, stream>>>(S);
  cvt_all<<<1024, t256, 0, stream>>>((const float4*)W_in, (const float4*)W_rec,
                                     (const float4*)W_out, (const float4*)x, S,
                                     (ushort4*)Wi_bf, (ushort4*)Wr_bf,
                                     (ushort4*)Wo_bf, (ushort4*)x_bf);

  Mods mods;
  for (int t = 0; t < 32; ++t) mods.m[t] = (float)(1.0 + 0.1 * sin(0.3 * (double)t));
  {
    void* args[] = {(void*)&x_bf, (void*)&Wi_bf, (void*)&Wr_bf, (void*)&b_in,
                    (void*)&b_rec, (void*)&hA, (void*)&hB, (void*)&bar, (void*)&mods};
    hipLaunchCooperativeKernel((const void*)rnn_coop, dim3(256), dim3(512),
                               args, 0, stream);
  }

  // out = h29 @ Wo_n^T + b_out
  gemm_bt0<<<dim3(B / 64, DOUT / 128), t256, 0, stream>>>(
      hB, Wo_bf, b_out, (float*)d_out, B, DOUT, H);
}